// Round 11
// baseline (1929.619 us; speedup 1.0000x reference)
//
#include <hip/hip_runtime.h>
#include <hip/hip_bf16.h>
#include <cstdint>
#include <cstddef>

// Problem dims (fixed by reference)
#define T_STEPS 500
#define BATCH   128
#define FDIM    128
#define HDIM    512
#define ODIM    32
#define M_ROWS  (T_STEPS * BATCH)   // 64000
#define ZOFF    (512u << 11)        // zero-row byte offset, fp32 WrecT (2 KB rows)
#define ZOFFB   (512u << 10)        // zero-row byte offset, bf16 WrecTb (1 KB rows)

typedef __attribute__((ext_vector_type(8))) __bf16 bf16x8;
typedef __attribute__((ext_vector_type(4))) float  f32x4;

__device__ __forceinline__ float bfbits2f(unsigned short u) {
    union { unsigned int i; float f; } c; c.i = ((unsigned int)u) << 16; return c.f;
}
__device__ __forceinline__ float asf(unsigned int u) {
    union { unsigned int i; float f; } c; c.i = u; return c.f;
}
// LDS-only barrier: NO vmcnt drain (all cross-thread comms in the scan are LDS).
// HARDENED: sched_barrier(0) on both sides pins compiler instruction motion
// across the barrier — raw __builtin_amdgcn_s_barrier() is NOT a compiler
// memory fence (rule #18 class; R2/R4 failures attributed to this).
__device__ __forceinline__ void lds_barrier() {
    __builtin_amdgcn_sched_barrier(0);
    asm volatile("s_waitcnt lgkmcnt(0)" ::: "memory");
    __builtin_amdgcn_s_barrier();
    __builtin_amdgcn_sched_barrier(0);
}

// ---------------------------------------------------------------------------
// Dtype detect: flag=1 means fp32 inputs, flag=0 means bf16.
// ---------------------------------------------------------------------------
__global__ void detect_kernel(const unsigned short* __restrict__ xw, int* __restrict__ flag) {
    __shared__ int cnt;
    if (threadIdx.x == 0) cnt = 0;
    __syncthreads();
    unsigned short w = xw[threadIdx.x * 2];
    int e = (w >> 7) & 0xFF;
    if (e >= 170) atomicAdd(&cnt, 1);
    __syncthreads();
    if (threadIdx.x == 0) *flag = (cnt >= 8) ? 1 : 0;
}

// ---------------------------------------------------------------------------
// Prep. flag==0 (bf16): WrecTb[hp][h] = raw bf16 bits of W_rec[h][hp] (+zero row).
//       flag==1 (fp32): WrecT fp32 transpose (+zero row), WinT fp32 transpose.
// WoutT (fp32 [h][o]) and bout32 built either way. WrecTb aliases WrecT storage.
// ---------------------------------------------------------------------------
__global__ void prep_kernel(const void* __restrict__ Wrec,
                            const void* __restrict__ Wout,
                            const void* __restrict__ bout,
                            const void* __restrict__ Win,
                            const int* __restrict__ flag,
                            float* __restrict__ WrecT,
                            unsigned short* __restrict__ WrecTb,
                            float* __restrict__ WoutT,
                            float* __restrict__ WinT,
                            float* __restrict__ bout32) {
    const int fp32 = *flag;
    int idx = blockIdx.x * blockDim.x + threadIdx.x;
    if (fp32) {
        if (idx < HDIM * HDIM) {
            int h = idx / HDIM, hp = idx % HDIM;
            WrecT[hp * HDIM + h] = ((const float*)Wrec)[idx];
        }
        if (idx < HDIM) WrecT[HDIM * HDIM + idx] = 0.f;
        if (idx < HDIM * FDIM) {
            int h = idx / FDIM, f = idx % FDIM;
            WinT[f * HDIM + h] = ((const float*)Win)[idx];
        }
    } else {
        if (idx < HDIM * HDIM) {
            int h = idx / HDIM, hp = idx % HDIM;
            WrecTb[hp * HDIM + h] = ((const unsigned short*)Wrec)[idx];
        }
        if (idx < HDIM) WrecTb[HDIM * HDIM + idx] = 0;
    }
    if (idx < ODIM * HDIM) {
        int o = idx / HDIM, h = idx % HDIM;
        WoutT[h * ODIM + o] = fp32 ? ((const float*)Wout)[idx]
                                   : bfbits2f(((const unsigned short*)Wout)[idx]);
    }
    if (idx < ODIM)
        bout32[idx] = fp32 ? ((const float*)bout)[idx]
                           : bfbits2f(((const unsigned short*)bout)[idx]);
}

// ---------------------------------------------------------------------------
// i_in GEMM, MFMA path (flag==0, bf16 inputs). 16x16x32 bf16 MFMA.
// ---------------------------------------------------------------------------
__global__ __launch_bounds__(256) void iin_gemm_mfma(const __hip_bfloat16* __restrict__ x,
                                                     const __hip_bfloat16* __restrict__ Win,
                                                     const int* __restrict__ flag,
                                                     float* __restrict__ iin) {
    if (*flag != 0) return;
    const int mt   = blockIdx.x;       // 0..999
    const int nt   = blockIdx.y;       // 0..7
    const int wave = threadIdx.x >> 6;
    const int lane = threadIdx.x & 63;
    const int l15  = lane & 15;
    const int quad = lane >> 4;
    const int m_base = mt * 64 + wave * 16;
    const int n_base = nt * 64;

    const __bf16* xb = reinterpret_cast<const __bf16*>(x);
    const __bf16* wb = reinterpret_cast<const __bf16*>(Win);

    f32x4 acc[4] = {{0.f,0.f,0.f,0.f},{0.f,0.f,0.f,0.f},{0.f,0.f,0.f,0.f},{0.f,0.f,0.f,0.f}};

#pragma unroll
    for (int kk = 0; kk < 4; ++kk) {
        const int k0 = kk * 32 + quad * 8;
        bf16x8 a = *reinterpret_cast<const bf16x8*>(xb + (size_t)(m_base + l15) * FDIM + k0);
#pragma unroll
        for (int nb = 0; nb < 4; ++nb) {
            bf16x8 bf = *reinterpret_cast<const bf16x8*>(wb + (size_t)(n_base + nb * 16 + l15) * FDIM + k0);
            acc[nb] = __builtin_amdgcn_mfma_f32_16x16x32_bf16(a, bf, acc[nb], 0, 0, 0);
        }
    }

#pragma unroll
    for (int nb = 0; nb < 4; ++nb)
#pragma unroll
        for (int r = 0; r < 4; ++r)
            iin[(size_t)(m_base + quad * 4 + r) * HDIM + n_base + nb * 16 + l15] = acc[nb][r];
}

// ---------------------------------------------------------------------------
// i_in GEMM, fp32 VALU fallback (flag==1) — R5 version (passing).
// ---------------------------------------------------------------------------
__global__ __launch_bounds__(256) void iin_gemm_valu(const void* __restrict__ x,
                                                     const float* __restrict__ WinT,
                                                     const int* __restrict__ flag,
                                                     float* __restrict__ iin) {
    if (*flag != 1) return;
    const int tid = threadIdx.x;
    const int m0  = blockIdx.x * 32;
    const int tg  = tid >> 6;          // m-group 0..3 -> rows tg*8..tg*8+7
    const int n0  = (tid & 63) * 8;    // output cols n0..n0+7

    __shared__ alignas(16) float xs[32][FDIM];   // 16 KB, [m][k]

    for (int i = tid; i < 32 * FDIM; i += 256)
        xs[0][i] = ((const float*)x)[(size_t)m0 * FDIM + i];
    __syncthreads();

    const float4* xs4 = reinterpret_cast<const float4*>(&xs[tg * 8][0]);

    float acc[8][8];
#pragma unroll
    for (int i = 0; i < 8; ++i)
#pragma unroll
        for (int j = 0; j < 8; ++j) acc[i][j] = 0.f;

    auto ldw = [&](int k4, float (*w)[8]) {
#pragma unroll
        for (int u = 0; u < 4; ++u) {
            const float* wp = WinT + (size_t)(k4 * 4 + u) * HDIM + n0;
            float4 a = *(const float4*)(wp);
            float4 b = *(const float4*)(wp + 4);
            w[u][0] = a.x; w[u][1] = a.y; w[u][2] = a.z; w[u][3] = a.w;
            w[u][4] = b.x; w[u][5] = b.y; w[u][6] = b.z; w[u][7] = b.w;
        }
    };
    auto cmp = [&](int k4, const float (*w)[8]) {
#pragma unroll
        for (int i = 0; i < 8; ++i) {
            float4 xv = xs4[i * (FDIM / 4) + k4];
#pragma unroll
            for (int j = 0; j < 8; ++j)
                acc[i][j] += xv.x * w[0][j] + xv.y * w[1][j]
                           + xv.z * w[2][j] + xv.w * w[3][j];
        }
    };

    float wA[4][8], wB[4][8];
    ldw(0, wA);
    for (int k4 = 0; k4 < FDIM / 4; k4 += 2) {
        ldw(k4 + 1, wB);
        cmp(k4, wA);
        if (k4 + 2 < FDIM / 4) ldw(k4 + 2, wA);
        cmp(k4 + 1, wB);
    }

#pragma unroll
    for (int i = 0; i < 8; ++i) {
        float4 lo = {acc[i][0], acc[i][1], acc[i][2], acc[i][3]};
        float4 hi = {acc[i][4], acc[i][5], acc[i][6], acc[i][7]};
        float* op = iin + (size_t)(m0 + tg * 8 + i) * HDIM + n0;
        *(float4*)(op)     = lo;
        *(float4*)(op + 4) = hi;
    }
}

// ---------------------------------------------------------------------------
// Scan, bf16-weight path (flag==0). 128 WGs, 1024 threads. (Unchanged, known good.)
// ---------------------------------------------------------------------------
__global__ __launch_bounds__(1024) void scan_bf16(const float* __restrict__ iin,
                                                  const unsigned short* __restrict__ WrecTb,
                                                  const int* __restrict__ flag,
                                                  unsigned long long* __restrict__ masksG) {
    if (*flag != 0) return;
    const int b    = blockIdx.x;
    const int tid  = threadIdx.x;
    const int q    = tid & 63;          // neuron octet base h = 8q
    const int pc   = tid >> 6;          // parity class (== wave) 0..15
    const int lane = tid & 63;
    const int wv   = tid >> 6;
    const bool st  = tid < HDIM;        // state-owning threads
    const int h    = tid;

    __shared__ unsigned long long wmask[8];
    __shared__ float4 partA[16][64];                    // 4 KB
    __shared__ float4 partB[16][64];                    // 4 KB
    __shared__ alignas(16) unsigned int slA[16][36];    // double-buffered lists
    __shared__ alignas(16) unsigned int slB[16][36];
    unsigned int (*slO)[36] = slA;
    unsigned int (*slN)[36] = slB;

    float v = 0.f, cur = 0.f, a = 0.f;
    int   cnt = 0;
    const char* WQ = (const char*)WrecTb + q * 16;   // + (hp<<10) -> row hp, cols 8q..8q+7
    float ic_cur = st ? iin[(size_t)b * HDIM + h] : 0.f;   // t = 0

    for (int t = 0; t < T_STEPS; ++t) {
        // prefetch next step's feed-forward current (slack ~ full step)
        float ic_next = 0.f;
        if (st && (t + 1) < T_STEPS)
            ic_next = iin[((size_t)(t + 1) * BATCH + b) * HDIM + h];

        float i_dec = 0.f; bool zk = false; unsigned long long m = 0;
        if (st) {
            float s = (0.0f - v) + 0.5f * expf((v - 1.0f) * 2.0f);
            s = s + cur;
            s = s - a;
            float v_dec = v + 0.1f * s;
            i_dec = cur - 0.2f * cur;
            float a_dec = a + 0.002f * (4.0f * v - a);
            zk = (v_dec - 1.0f) > 0.0f;
            m = __ballot(zk);
            if (lane == 0) {
                wmask[wv] = m;
                masksG[((size_t)t * BATCH + b) * 8 + wv] = m;   // fire-and-forget
            }
            v = zk ? 0.0f : v_dec;
            a = zk ? (a_dec + 0.02f) : a_dec;
        }

        // ---- gather my parity class of PREVIOUS spikes (8 weights / load) ----
        float rs0=0.f,rs1=0.f,rs2=0.f,rs3=0.f,rs4=0.f,rs5=0.f,rs6=0.f,rs7=0.f;
        {
            const unsigned int* sl = slO[pc];
            const int n  = (cnt + 15 - pc) >> 4;   // my sub-list length
            const int ng = (n + 3) >> 2;           // padded groups of 4
            uint4 w0[4], w1[4];
            auto ldg = [&](int g, uint4* w) {
                uint4 ix = *(const uint4*)(sl + (g << 2));   // wave-uniform b128
                w[0] = *(const uint4*)(WQ + ix.x);
                w[1] = *(const uint4*)(WQ + ix.y);
                w[2] = *(const uint4*)(WQ + ix.z);
                w[3] = *(const uint4*)(WQ + ix.w);
            };
            auto accw = [&](const uint4* w) {
#pragma unroll
                for (int u = 0; u < 4; ++u) {
                    rs0 += asf(w[u].x << 16); rs1 += asf(w[u].x & 0xffff0000u);
                    rs2 += asf(w[u].y << 16); rs3 += asf(w[u].y & 0xffff0000u);
                    rs4 += asf(w[u].z << 16); rs5 += asf(w[u].z & 0xffff0000u);
                    rs6 += asf(w[u].w << 16); rs7 += asf(w[u].w & 0xffff0000u);
                }
            };
            int g = 0;
            if (ng > 0) ldg(0, w0);
            while (g + 2 <= ng) {
                ldg(g + 1, w1);
                accw(w0);
                if (g + 2 < ng) ldg(g + 2, w0);
                accw(w1);
                g += 2;
            }
            if (g < ng) accw(w0);
        }
        partA[pc][q] = (float4){rs0, rs1, rs2, rs3};
        partB[pc][q] = (float4){rs4, rs5, rs6, rs7};

        lds_barrier();   // B1: wmask + partials visible; slO fully consumed

        int total = 0;
#pragma unroll
        for (int w = 0; w < 8; ++w) total += __popcll(wmask[w]);

        if (st) {
            // combine partials, ascending pc (deterministic)
            float rec = 0.f;
            const int  qq = h >> 3, jj = h & 3;
            const bool hi = (h & 4) != 0;
#pragma unroll
            for (int pp = 0; pp < 16; ++pp) {
                const float* pa = (const float*)&partA[pp][qq];
                const float* pb = (const float*)&partB[pp][qq];
                rec += hi ? pb[jj] : pa[jj];
            }
            cur = (i_dec + ic_cur) + rec;

            if (zk) {
                int off = __popcll(m & ((1ull << lane) - 1ull));
#pragma unroll
                for (int w = 0; w < 8; ++w) if (w < wv) off += __popcll(wmask[w]);
                slN[off & 15][off >> 4] = (unsigned int)h << 10;
            }
        } else if (tid < HDIM + 64) {
            // zero-row padding: sub-list s5 padded to multiple of 4
            int s5 = (tid - HDIM) >> 2;
            int k  = (tid - HDIM) & 3;
            int ne = (total + 15 - s5) >> 4;
            int padc = (4 - (ne & 3)) & 3;
            if (k < padc) slN[s5][ne + k] = ZOFFB;
        }
        cnt = total;
        ic_cur = ic_next;

        lds_barrier();   // B2: new lists complete before next step's gather

        unsigned int (*tp)[36] = slO; slO = slN; slN = tp;
    }
}

// ---------------------------------------------------------------------------
// Scan, fp32 path (flag==1) — R11: R10 structure (548us, proven) + FUSED
// y+filter role on wave 8's post-barrier idle slot.
//
// Pre-barrier: identical to R10 (state waves 0-7 update + write seg/scnt;
// all 16 waves gather seg[pv] -> part[cb]). masksG stores DROPPED (consumer
// y_kernel is now bf16-only).
//
// Post-barrier: state threads combine (as R10). NEW: wave 8 (threads
// 512-575; its gather role is pre-barrier, its post-barrier slot was idle)
// computes y[t][b][o] from THIS step's spike lists seg[cb]/scnt[cb]
// (complete + visible after the barrier):
//   thread (o = lane&31, half = lane>>5) sums WoutT[hp][o] over the 4
//   segments of its half (real counts only, ascending seg/rank = ascending
//   h, same order as y_kernel), __shfl_xor(32) combines halves, + bout[o],
//   then applies the exponential-filter recurrence in-register and half-0
//   writes out[t][b][o] (coalesced 128B store). Eliminates y_kernel +
//   filter_kernel + masksG traffic from the fp32 path.
//
// Hazards: y-role reads seg/scnt[cb] AFTER barrier(t); that buffer is next
// rewritten at t+2 after barrier(t+1) — reads complete before this wave
// reaches barrier(t+1) (program order), same proven pattern as combine/part.
// ---------------------------------------------------------------------------
__global__ __launch_bounds__(1024) void scan_f32(const float* __restrict__ iin,
                                                 const float* __restrict__ WrecT,
                                                 const int* __restrict__ flag,
                                                 const float* __restrict__ WoutT,
                                                 const float* __restrict__ bout32,
                                                 float* __restrict__ outF) {
    if (*flag != 1) return;
    const int b    = blockIdx.x;
    const int tid  = threadIdx.x;
    const int lane = tid & 63;
    const int wv   = tid >> 6;          // 0..15
    const bool st  = tid < HDIM;
    const int h    = tid;               // neuron index (st threads)
    const int p    = tid >> 7;          // gather class == segment 0..7
    const int q    = tid & 127;         // 16B column block (cols 4q..4q+3)

    __shared__ alignas(16) unsigned int seg[2][8][64];  // 4 KB: byte offs hp<<11
    __shared__ int scnt[2][8];
    __shared__ float4 part[2][8][128];                  // 32 KB

    // init prev-buffer (index 1): empty lists, valid ZOFF targets
    if (tid < 8) scnt[1][tid] = 0;
    if (tid < 512) ((unsigned int*)seg[1])[tid] = ZOFF;
    lds_barrier();

    // prioritize the critical-path (state) waves; wave-uniform branch
    if (st) __builtin_amdgcn_s_setprio(1);

    float v = 0.f, cur = 0.f, a = 0.f;
    const char* WQ = (const char*)WrecT + q * 16;

    // 2-deep iin prefetch registers (consumed at body t, reloaded t+2)
    float icE = st ? iin[((size_t)0 * BATCH + b) * HDIM + h] : 0.f;
    float icO = st ? iin[((size_t)1 * BATCH + b) * HDIM + h] : 0.f;

    // y+filter role: wave 8 (threads 512-575)
    const bool yrole = (wv == 8);
    const int  yo    = lane & 31;       // output index o
    const int  yhalf = lane >> 5;       // segments yhalf*4 .. yhalf*4+3
    float o_state = 0.f;
    float bo = yrole ? bout32[yo] : 0.f;
    const char* WoB = (const char*)WoutT + (yo << 2);   // + (hp<<7) -> WoutT[hp][yo]

    auto body = [&](int t, int cb, float& icReg) {
        const int pv = cb ^ 1;

        // ---- 1. state update + segment-list write (st threads) ----
        float i_dec = 0.f;
        if (st) {
            float s = (0.0f - v) + 0.5f * expf((v - 1.0f) * 2.0f);
            s = s + cur;
            s = s - a;
            float v_dec = v + 0.1f * s;
            i_dec = cur - 0.2f * cur;
            float a_dec = a + 0.002f * (4.0f * v - a);
            bool  zk = (v_dec - 1.0f) > 0.0f;
            unsigned long long m = __ballot(zk);
            int c = (int)__popcll(m);
            unsigned long long below = (1ull << lane) - 1ull;
            if (lane == 0) scnt[cb][wv] = c;
            if (zk) {
                int off = (int)__popcll(m & below);
                seg[cb][wv][off] = (unsigned int)h << 11;
            } else {
                int pe = (c + 3) & ~3; pe = (pe < 4) ? 4 : pe;  // pad to x4, min 4
                int ip = c + (int)__popcll(~m & below);
                if (ip < pe) seg[cb][wv][ip] = ZOFF;
            }
            v = zk ? 0.0f : v_dec;
            a = zk ? (a_dec + 0.02f) : a_dec;
        }

        // ---- 2. gather segment p of z(t-1) spikes (all threads) ----
        {
            const int n  = scnt[pv][p];            // wave-uniform
            const int ng = (n + 3) >> 2;
            const unsigned int* sp = &seg[pv][p][0];
            float4 rs = {0.f, 0.f, 0.f, 0.f};
            float4 b0[4], b1[4];
            auto ld4 = [&](int g, float4* d) {
                uint4 i0 = *(const uint4*)(sp + (g << 2));   // wave-uniform b128
                d[0] = *(const float4*)(WQ + i0.x);
                d[1] = *(const float4*)(WQ + i0.y);
                d[2] = *(const float4*)(WQ + i0.z);
                d[3] = *(const float4*)(WQ + i0.w);
            };
            auto acc4 = [&](const float4* d) {
#pragma unroll
                for (int u = 0; u < 4; ++u) {
                    rs.x += d[u].x; rs.y += d[u].y; rs.z += d[u].z; rs.w += d[u].w;
                }
            };
            ld4(0, b0);   // unconditional: entries 0..3 always real or ZOFF
            int g = 0;
            while (g + 2 <= ng) {
                ld4(g + 1, b1);
                acc4(b0);
                if (g + 2 < ng) ld4(g + 2, b0);
                acc4(b1);
                g += 2;
            }
            if (g < ng) acc4(b0);
            part[cb][p][q] = rs;
        }

        lds_barrier();   // the ONE barrier per step

        // ---- 4a. combine partials -> cur(t) (st threads) ----
        if (st) {
            float rec = 0.f;
#pragma unroll
            for (int pp = 0; pp < 8; ++pp)
                rec += ((const float*)&part[cb][pp][h >> 2])[h & 3];
            cur = (i_dec + icReg) + rec;          // consume iin[t] (2 steps old)
            if (t + 2 < T_STEPS)                  // reissue for t+2
                icReg = iin[((size_t)(t + 2) * BATCH + b) * HDIM + h];
        } else if (yrole) {
            // ---- 4b. fused y + exp-filter from THIS step's spikes seg[cb] ----
            float acc = 0.f;
#pragma unroll
            for (int s5 = 0; s5 < 4; ++s5) {
                const int s = yhalf * 4 + s5;
                const int c = scnt[cb][s];
                const unsigned int* sp = &seg[cb][s][0];
                for (int e = 0; e < c; ++e)
                    acc += *(const float*)(WoB + (sp[e] >> 4));   // hp<<11 -> hp<<7
            }
            float ytot = acc + __shfl_xor(acc, 32);
            float yv = ytot + bo;
            o_state = (t == 0) ? yv : (o_state + 0.2231435511314f * (yv - o_state));
            if (yhalf == 0)
                outF[(size_t)t * (BATCH * ODIM) + b * ODIM + yo] = o_state;
        }
    };

    for (int t = 0; t < T_STEPS; t += 2) {
        body(t,     0, icE);
        body(t + 1, 1, icO);
    }
}

// ---------------------------------------------------------------------------
// Readout from spike masks (bf16 path ONLY; fp32 path is fused into scan_f32).
// ---------------------------------------------------------------------------
__global__ __launch_bounds__(256) void y_kernel(const unsigned long long* __restrict__ masks,
                                                const float* __restrict__ WoutT,
                                                const float* __restrict__ bout,
                                                const int* __restrict__ flag,
                                                float* __restrict__ y) {
    if (*flag != 0) return;
    const int tid = threadIdx.x;
    const int p   = blockIdx.x * 8 + (tid >> 5);   // t*BATCH + b
    const int o   = tid & 31;
    const unsigned long long* mp = masks + (size_t)p * 8;
    float acc = 0.f;
#pragma unroll
    for (int w = 0; w < 8; ++w) {
        unsigned long long m = mp[w];
        const float* Wb = WoutT + (size_t)w * 64 * ODIM + o;
        while (m) {
            int j = __builtin_ctzll(m);
            acc += Wb[j * ODIM];
            m &= m - 1;
        }
    }
    y[(size_t)p * ODIM + o] = acc + bout[o];
}

// ---------------------------------------------------------------------------
// Exponential filter over t (bf16 path ONLY; fp32 fused into scan_f32).
// ---------------------------------------------------------------------------
__global__ __launch_bounds__(64) void filter_kernel(const float* __restrict__ y,
                                                    const int* __restrict__ flag,
                                                    void* __restrict__ out) {
    if (*flag != 0) return;
    const int p = blockIdx.x * 64 + threadIdx.x;   // b*ODIM + o
    const float kf = 0.2231435511314f;   // DT*TAU_FILTER_INV
    float c0[10], c1[10];
#pragma unroll
    for (int u = 0; u < 10; ++u) c0[u] = y[(size_t)u * (BATCH * ODIM) + p];
    float o_state = 0.f;
    for (int base = 0; base < T_STEPS; base += 10) {
        if (base + 10 < T_STEPS) {
#pragma unroll
            for (int u = 0; u < 10; ++u)
                c1[u] = y[(size_t)(base + 10 + u) * (BATCH * ODIM) + p];
        }
#pragma unroll
        for (int u = 0; u < 10; ++u) {
            int t = base + u;
            float yt = c0[u];
            o_state = (t == 0) ? yt : (o_state + kf * (yt - o_state));
            size_t oi = (size_t)t * (BATCH * ODIM) + p;
            ((__hip_bfloat16*)out)[oi] = __float2bfloat16(o_state);
        }
#pragma unroll
        for (int u = 0; u < 10; ++u) c0[u] = c1[u];
    }
}

// ---------------------------------------------------------------------------
extern "C" void kernel_launch(void* const* d_in, const int* in_sizes, int n_in,
                              void* d_out, int out_size, void* d_ws, size_t ws_size,
                              hipStream_t stream) {
    // select inputs by unique element count (robust to ordering)
    const void* x = d_in[0]; const void* Win = d_in[1]; const void* Wrec = d_in[2];
    const void* Wout = d_in[3]; const void* bout = d_in[4];
    for (int i = 0; i < n_in; ++i) {
        switch (in_sizes[i]) {
            case 8192000: x    = d_in[i]; break;
            case 65536:   Win  = d_in[i]; break;
            case 262144:  Wrec = d_in[i]; break;
            case 16384:   Wout = d_in[i]; break;
            case 32:      bout = d_in[i]; break;
            default: break;
        }
    }

    // workspace layout (bytes) — WrecTb (bf16) aliases WrecT (fp32) storage
    const size_t OFF_FLAG  = 0;          // 4
    const size_t OFF_BOUT  = 256;        // 128
    const size_t OFF_WOUTT = 512;        // 65536
    const size_t OFF_WRECT = 66048;      // 513*512*4 = 1050624 (or 513*512*2 bf16)
    const size_t OFF_WINT  = 1116672;    // 262144
    const size_t OFF_MASK  = 1378816;    // 500*128*8*8 = 4096000
    const size_t OFF_IIN   = 5474816;    // 64000*512*4 = 131072000
    const size_t OFF_Y     = OFF_IIN;    // y (8.2 MB) aliases iin (dead after scan)
    const size_t REQUIRED  = OFF_IIN + (size_t)M_ROWS * HDIM * 4;  // 136546816
    if (ws_size < REQUIRED) return;  // diagnostic: output stays 0

    char* ws = (char*)d_ws;
    int*            flag   = (int*)(ws + OFF_FLAG);
    float*          bout32 = (float*)(ws + OFF_BOUT);
    float*          WoutT  = (float*)(ws + OFF_WOUTT);
    float*          WrecT  = (float*)(ws + OFF_WRECT);
    unsigned short* WrecTb = (unsigned short*)(ws + OFF_WRECT);
    float*          WinT   = (float*)(ws + OFF_WINT);
    unsigned long long* masks = (unsigned long long*)(ws + OFF_MASK);
    float*          iin    = (float*)(ws + OFF_IIN);
    float*          y      = (float*)(ws + OFF_Y);

    hipLaunchKernelGGL(detect_kernel, dim3(1), dim3(256), 0, stream,
                       (const unsigned short*)x, flag);
    hipLaunchKernelGGL(prep_kernel, dim3((HDIM * HDIM + 255) / 256), dim3(256), 0, stream,
                       Wrec, Wout, bout, Win, flag, WrecT, WrecTb, WoutT, WinT, bout32);
    hipLaunchKernelGGL(iin_gemm_mfma, dim3(M_ROWS / 64, HDIM / 64), dim3(256), 0, stream,
                       (const __hip_bfloat16*)x, (const __hip_bfloat16*)Win, flag, iin);
    hipLaunchKernelGGL(iin_gemm_valu, dim3(M_ROWS / 32), dim3(256), 0, stream,
                       x, WinT, flag, iin);
    hipLaunchKernelGGL(scan_bf16, dim3(BATCH), dim3(1024), 0, stream,
                       iin, WrecTb, flag, masks);
    hipLaunchKernelGGL(scan_f32, dim3(BATCH), dim3(1024), 0, stream,
                       iin, WrecT, flag, WoutT, bout32, (float*)d_out);
    hipLaunchKernelGGL(y_kernel, dim3(M_ROWS / 8), dim3(256), 0, stream,
                       masks, WoutT, bout32, flag, y);
    hipLaunchKernelGGL(filter_kernel, dim3((BATCH * ODIM) / 64), dim3(64), 0, stream,
                       y, flag, d_out);
}

// Round 12
// 1130.314 us; speedup vs baseline: 1.7072x; 1.7072x over previous
//
#include <hip/hip_runtime.h>
#include <hip/hip_bf16.h>
#include <cstdint>
#include <cstddef>

// Problem dims (fixed by reference)
#define T_STEPS 500
#define BATCH   128
#define FDIM    128
#define HDIM    512
#define ODIM    32
#define M_ROWS  (T_STEPS * BATCH)   // 64000
#define ZOFF    (512u << 11)        // zero-row byte offset, fp32 WrecT (2 KB rows)
#define ZOFFB   (512u << 10)        // zero-row byte offset, bf16 WrecTb (1 KB rows)

typedef __attribute__((ext_vector_type(8))) __bf16 bf16x8;
typedef __attribute__((ext_vector_type(4))) float  f32x4;

__device__ __forceinline__ float bfbits2f(unsigned short u) {
    union { unsigned int i; float f; } c; c.i = ((unsigned int)u) << 16; return c.f;
}
__device__ __forceinline__ float asf(unsigned int u) {
    union { unsigned int i; float f; } c; c.i = u; return c.f;
}
// LDS-only barrier: NO vmcnt drain (all cross-thread comms in the scan are LDS).
// HARDENED: sched_barrier(0) on both sides pins compiler instruction motion
// across the barrier — raw __builtin_amdgcn_s_barrier() is NOT a compiler
// memory fence (rule #18 class; R2/R4 failures attributed to this).
__device__ __forceinline__ void lds_barrier() {
    __builtin_amdgcn_sched_barrier(0);
    asm volatile("s_waitcnt lgkmcnt(0)" ::: "memory");
    __builtin_amdgcn_s_barrier();
    __builtin_amdgcn_sched_barrier(0);
}

// ---------------------------------------------------------------------------
// Dtype detect: flag=1 means fp32 inputs, flag=0 means bf16.
// ---------------------------------------------------------------------------
__global__ void detect_kernel(const unsigned short* __restrict__ xw, int* __restrict__ flag) {
    __shared__ int cnt;
    if (threadIdx.x == 0) cnt = 0;
    __syncthreads();
    unsigned short w = xw[threadIdx.x * 2];
    int e = (w >> 7) & 0xFF;
    if (e >= 170) atomicAdd(&cnt, 1);
    __syncthreads();
    if (threadIdx.x == 0) *flag = (cnt >= 8) ? 1 : 0;
}

// ---------------------------------------------------------------------------
// Prep. flag==0 (bf16): WrecTb[hp][h] = raw bf16 bits of W_rec[h][hp] (+zero row).
//       flag==1 (fp32): WrecT fp32 transpose (+zero row), WinT fp32 transpose.
// WoutT (fp32 [h][o]) and bout32 built either way. WrecTb aliases WrecT storage.
// ---------------------------------------------------------------------------
__global__ void prep_kernel(const void* __restrict__ Wrec,
                            const void* __restrict__ Wout,
                            const void* __restrict__ bout,
                            const void* __restrict__ Win,
                            const int* __restrict__ flag,
                            float* __restrict__ WrecT,
                            unsigned short* __restrict__ WrecTb,
                            float* __restrict__ WoutT,
                            float* __restrict__ WinT,
                            float* __restrict__ bout32) {
    const int fp32 = *flag;
    int idx = blockIdx.x * blockDim.x + threadIdx.x;
    if (fp32) {
        if (idx < HDIM * HDIM) {
            int h = idx / HDIM, hp = idx % HDIM;
            WrecT[hp * HDIM + h] = ((const float*)Wrec)[idx];
        }
        if (idx < HDIM) WrecT[HDIM * HDIM + idx] = 0.f;
        if (idx < HDIM * FDIM) {
            int h = idx / FDIM, f = idx % FDIM;
            WinT[f * HDIM + h] = ((const float*)Win)[idx];
        }
    } else {
        if (idx < HDIM * HDIM) {
            int h = idx / HDIM, hp = idx % HDIM;
            WrecTb[hp * HDIM + h] = ((const unsigned short*)Wrec)[idx];
        }
        if (idx < HDIM) WrecTb[HDIM * HDIM + idx] = 0;
    }
    if (idx < ODIM * HDIM) {
        int o = idx / HDIM, h = idx % HDIM;
        WoutT[h * ODIM + o] = fp32 ? ((const float*)Wout)[idx]
                                   : bfbits2f(((const unsigned short*)Wout)[idx]);
    }
    if (idx < ODIM)
        bout32[idx] = fp32 ? ((const float*)bout)[idx]
                           : bfbits2f(((const unsigned short*)bout)[idx]);
}

// ---------------------------------------------------------------------------
// i_in GEMM, MFMA path (flag==0, bf16 inputs). 16x16x32 bf16 MFMA.
// ---------------------------------------------------------------------------
__global__ __launch_bounds__(256) void iin_gemm_mfma(const __hip_bfloat16* __restrict__ x,
                                                     const __hip_bfloat16* __restrict__ Win,
                                                     const int* __restrict__ flag,
                                                     float* __restrict__ iin) {
    if (*flag != 0) return;
    const int mt   = blockIdx.x;       // 0..999
    const int nt   = blockIdx.y;       // 0..7
    const int wave = threadIdx.x >> 6;
    const int lane = threadIdx.x & 63;
    const int l15  = lane & 15;
    const int quad = lane >> 4;
    const int m_base = mt * 64 + wave * 16;
    const int n_base = nt * 64;

    const __bf16* xb = reinterpret_cast<const __bf16*>(x);
    const __bf16* wb = reinterpret_cast<const __bf16*>(Win);

    f32x4 acc[4] = {{0.f,0.f,0.f,0.f},{0.f,0.f,0.f,0.f},{0.f,0.f,0.f,0.f},{0.f,0.f,0.f,0.f}};

#pragma unroll
    for (int kk = 0; kk < 4; ++kk) {
        const int k0 = kk * 32 + quad * 8;
        bf16x8 a = *reinterpret_cast<const bf16x8*>(xb + (size_t)(m_base + l15) * FDIM + k0);
#pragma unroll
        for (int nb = 0; nb < 4; ++nb) {
            bf16x8 bf = *reinterpret_cast<const bf16x8*>(wb + (size_t)(n_base + nb * 16 + l15) * FDIM + k0);
            acc[nb] = __builtin_amdgcn_mfma_f32_16x16x32_bf16(a, bf, acc[nb], 0, 0, 0);
        }
    }

#pragma unroll
    for (int nb = 0; nb < 4; ++nb)
#pragma unroll
        for (int r = 0; r < 4; ++r)
            iin[(size_t)(m_base + quad * 4 + r) * HDIM + n_base + nb * 16 + l15] = acc[nb][r];
}

// ---------------------------------------------------------------------------
// i_in GEMM, fp32 VALU fallback (flag==1) — R5 version (passing).
// ---------------------------------------------------------------------------
__global__ __launch_bounds__(256) void iin_gemm_valu(const void* __restrict__ x,
                                                     const float* __restrict__ WinT,
                                                     const int* __restrict__ flag,
                                                     float* __restrict__ iin) {
    if (*flag != 1) return;
    const int tid = threadIdx.x;
    const int m0  = blockIdx.x * 32;
    const int tg  = tid >> 6;          // m-group 0..3 -> rows tg*8..tg*8+7
    const int n0  = (tid & 63) * 8;    // output cols n0..n0+7

    __shared__ alignas(16) float xs[32][FDIM];   // 16 KB, [m][k]

    for (int i = tid; i < 32 * FDIM; i += 256)
        xs[0][i] = ((const float*)x)[(size_t)m0 * FDIM + i];
    __syncthreads();

    const float4* xs4 = reinterpret_cast<const float4*>(&xs[tg * 8][0]);

    float acc[8][8];
#pragma unroll
    for (int i = 0; i < 8; ++i)
#pragma unroll
        for (int j = 0; j < 8; ++j) acc[i][j] = 0.f;

    auto ldw = [&](int k4, float (*w)[8]) {
#pragma unroll
        for (int u = 0; u < 4; ++u) {
            const float* wp = WinT + (size_t)(k4 * 4 + u) * HDIM + n0;
            float4 a = *(const float4*)(wp);
            float4 b = *(const float4*)(wp + 4);
            w[u][0] = a.x; w[u][1] = a.y; w[u][2] = a.z; w[u][3] = a.w;
            w[u][4] = b.x; w[u][5] = b.y; w[u][6] = b.z; w[u][7] = b.w;
        }
    };
    auto cmp = [&](int k4, const float (*w)[8]) {
#pragma unroll
        for (int i = 0; i < 8; ++i) {
            float4 xv = xs4[i * (FDIM / 4) + k4];
#pragma unroll
            for (int j = 0; j < 8; ++j)
                acc[i][j] += xv.x * w[0][j] + xv.y * w[1][j]
                           + xv.z * w[2][j] + xv.w * w[3][j];
        }
    };

    float wA[4][8], wB[4][8];
    ldw(0, wA);
    for (int k4 = 0; k4 < FDIM / 4; k4 += 2) {
        ldw(k4 + 1, wB);
        cmp(k4, wA);
        if (k4 + 2 < FDIM / 4) ldw(k4 + 2, wA);
        cmp(k4 + 1, wB);
    }

#pragma unroll
    for (int i = 0; i < 8; ++i) {
        float4 lo = {acc[i][0], acc[i][1], acc[i][2], acc[i][3]};
        float4 hi = {acc[i][4], acc[i][5], acc[i][6], acc[i][7]};
        float* op = iin + (size_t)(m0 + tg * 8 + i) * HDIM + n0;
        *(float4*)(op)     = lo;
        *(float4*)(op + 4) = hi;
    }
}

// ---------------------------------------------------------------------------
// Scan, bf16-weight path (flag==0). 128 WGs, 1024 threads. (Unchanged, known good.)
// ---------------------------------------------------------------------------
__global__ __launch_bounds__(1024) void scan_bf16(const float* __restrict__ iin,
                                                  const unsigned short* __restrict__ WrecTb,
                                                  const int* __restrict__ flag,
                                                  unsigned long long* __restrict__ masksG) {
    if (*flag != 0) return;
    const int b    = blockIdx.x;
    const int tid  = threadIdx.x;
    const int q    = tid & 63;          // neuron octet base h = 8q
    const int pc   = tid >> 6;          // parity class (== wave) 0..15
    const int lane = tid & 63;
    const int wv   = tid >> 6;
    const bool st  = tid < HDIM;        // state-owning threads
    const int h    = tid;

    __shared__ unsigned long long wmask[8];
    __shared__ float4 partA[16][64];                    // 4 KB
    __shared__ float4 partB[16][64];                    // 4 KB
    __shared__ alignas(16) unsigned int slA[16][36];    // double-buffered lists
    __shared__ alignas(16) unsigned int slB[16][36];
    unsigned int (*slO)[36] = slA;
    unsigned int (*slN)[36] = slB;

    float v = 0.f, cur = 0.f, a = 0.f;
    int   cnt = 0;
    const char* WQ = (const char*)WrecTb + q * 16;   // + (hp<<10) -> row hp, cols 8q..8q+7
    float ic_cur = st ? iin[(size_t)b * HDIM + h] : 0.f;   // t = 0

    for (int t = 0; t < T_STEPS; ++t) {
        // prefetch next step's feed-forward current (slack ~ full step)
        float ic_next = 0.f;
        if (st && (t + 1) < T_STEPS)
            ic_next = iin[((size_t)(t + 1) * BATCH + b) * HDIM + h];

        float i_dec = 0.f; bool zk = false; unsigned long long m = 0;
        if (st) {
            float s = (0.0f - v) + 0.5f * expf((v - 1.0f) * 2.0f);
            s = s + cur;
            s = s - a;
            float v_dec = v + 0.1f * s;
            i_dec = cur - 0.2f * cur;
            float a_dec = a + 0.002f * (4.0f * v - a);
            zk = (v_dec - 1.0f) > 0.0f;
            m = __ballot(zk);
            if (lane == 0) {
                wmask[wv] = m;
                masksG[((size_t)t * BATCH + b) * 8 + wv] = m;   // fire-and-forget
            }
            v = zk ? 0.0f : v_dec;
            a = zk ? (a_dec + 0.02f) : a_dec;
        }

        // ---- gather my parity class of PREVIOUS spikes (8 weights / load) ----
        float rs0=0.f,rs1=0.f,rs2=0.f,rs3=0.f,rs4=0.f,rs5=0.f,rs6=0.f,rs7=0.f;
        {
            const unsigned int* sl = slO[pc];
            const int n  = (cnt + 15 - pc) >> 4;   // my sub-list length
            const int ng = (n + 3) >> 2;           // padded groups of 4
            uint4 w0[4], w1[4];
            auto ldg = [&](int g, uint4* w) {
                uint4 ix = *(const uint4*)(sl + (g << 2));   // wave-uniform b128
                w[0] = *(const uint4*)(WQ + ix.x);
                w[1] = *(const uint4*)(WQ + ix.y);
                w[2] = *(const uint4*)(WQ + ix.z);
                w[3] = *(const uint4*)(WQ + ix.w);
            };
            auto accw = [&](const uint4* w) {
#pragma unroll
                for (int u = 0; u < 4; ++u) {
                    rs0 += asf(w[u].x << 16); rs1 += asf(w[u].x & 0xffff0000u);
                    rs2 += asf(w[u].y << 16); rs3 += asf(w[u].y & 0xffff0000u);
                    rs4 += asf(w[u].z << 16); rs5 += asf(w[u].z & 0xffff0000u);
                    rs6 += asf(w[u].w << 16); rs7 += asf(w[u].w & 0xffff0000u);
                }
            };
            int g = 0;
            if (ng > 0) ldg(0, w0);
            while (g + 2 <= ng) {
                ldg(g + 1, w1);
                accw(w0);
                if (g + 2 < ng) ldg(g + 2, w0);
                accw(w1);
                g += 2;
            }
            if (g < ng) accw(w0);
        }
        partA[pc][q] = (float4){rs0, rs1, rs2, rs3};
        partB[pc][q] = (float4){rs4, rs5, rs6, rs7};

        lds_barrier();   // B1: wmask + partials visible; slO fully consumed

        int total = 0;
#pragma unroll
        for (int w = 0; w < 8; ++w) total += __popcll(wmask[w]);

        if (st) {
            // combine partials, ascending pc (deterministic)
            float rec = 0.f;
            const int  qq = h >> 3, jj = h & 3;
            const bool hi = (h & 4) != 0;
#pragma unroll
            for (int pp = 0; pp < 16; ++pp) {
                const float* pa = (const float*)&partA[pp][qq];
                const float* pb = (const float*)&partB[pp][qq];
                rec += hi ? pb[jj] : pa[jj];
            }
            cur = (i_dec + ic_cur) + rec;

            if (zk) {
                int off = __popcll(m & ((1ull << lane) - 1ull));
#pragma unroll
                for (int w = 0; w < 8; ++w) if (w < wv) off += __popcll(wmask[w]);
                slN[off & 15][off >> 4] = (unsigned int)h << 10;
            }
        } else if (tid < HDIM + 64) {
            // zero-row padding: sub-list s5 padded to multiple of 4
            int s5 = (tid - HDIM) >> 2;
            int k  = (tid - HDIM) & 3;
            int ne = (total + 15 - s5) >> 4;
            int padc = (4 - (ne & 3)) & 3;
            if (k < padc) slN[s5][ne + k] = ZOFFB;
        }
        cnt = total;
        ic_cur = ic_next;

        lds_barrier();   // B2: new lists complete before next step's gather

        unsigned int (*tp)[36] = slO; slO = slN; slN = tp;
    }
}

// ---------------------------------------------------------------------------
// Scan, fp32 path (flag==1) — R12: R10 structure + fused y+filter on wave 8,
// now with PARALLEL static-address y-role (R11's serial walk was the 3.2x
// regression; R11 proved the fusion's CORRECTNESS — absmax 9.77e-4).
//
// Writer change vs R10: segments padded to x8 (min 8) with ZOFF. Gather
// arithmetic provably unchanged (gather reads < (c+3)&~3 <= new pe).
//
// y-role (wave 8, post-barrier): fixed 8 entries/segment via 2 broadcast
// uint4 LDS reads x 8 segs; lane (o=lane&31, ep=lane>>5) takes parity-ep
// entries -> 32 INDEPENDENT coalesced loads (WoutT row = 32 lanes x 4B).
// Pad entries masked by (a==ZOFF ? 0 : val) — the ZOFF-offset load lands in
// valid workspace memory (WrecT row 0), value discarded. Rare c>8 tail
// loops over real entries only. __shfl_xor(32) combines parities, + bias,
// in-register exp-filter, half-0 stores out[t][b][o] (coalesced 128B).
// ---------------------------------------------------------------------------
__global__ __launch_bounds__(1024) void scan_f32(const float* __restrict__ iin,
                                                 const float* __restrict__ WrecT,
                                                 const int* __restrict__ flag,
                                                 const float* __restrict__ WoutT,
                                                 const float* __restrict__ bout32,
                                                 float* __restrict__ outF) {
    if (*flag != 1) return;
    const int b    = blockIdx.x;
    const int tid  = threadIdx.x;
    const int lane = tid & 63;
    const int wv   = tid >> 6;          // 0..15
    const bool st  = tid < HDIM;
    const int h    = tid;               // neuron index (st threads)
    const int p    = tid >> 7;          // gather class == segment 0..7
    const int q    = tid & 127;         // 16B column block (cols 4q..4q+3)

    __shared__ alignas(16) unsigned int seg[2][8][64];  // 4 KB: byte offs hp<<11
    __shared__ int scnt[2][8];
    __shared__ float4 part[2][8][128];                  // 32 KB

    // init prev-buffer (index 1): empty lists, valid ZOFF targets
    if (tid < 8) scnt[1][tid] = 0;
    if (tid < 512) ((unsigned int*)seg[1])[tid] = ZOFF;
    lds_barrier();

    // prioritize the critical-path (state) waves; wave-uniform branch
    if (st) __builtin_amdgcn_s_setprio(1);

    float v = 0.f, cur = 0.f, a = 0.f;
    const char* WQ = (const char*)WrecT + q * 16;

    // 2-deep iin prefetch registers (consumed at body t, reloaded t+2)
    float icE = st ? iin[((size_t)0 * BATCH + b) * HDIM + h] : 0.f;
    float icO = st ? iin[((size_t)1 * BATCH + b) * HDIM + h] : 0.f;

    // y+filter role: wave 8 (threads 512-575)
    const bool yrole = (wv == 8);
    const int  yo    = lane & 31;       // output index o
    const int  yep   = lane >> 5;       // entry parity 0/1
    float o_state = 0.f;
    float bo = yrole ? bout32[yo] : 0.f;
    const char* WoB = (const char*)WoutT + (yo << 2);   // + (hp<<7) -> WoutT[hp][yo]

    auto body = [&](int t, int cb, float& icReg) {
        const int pv = cb ^ 1;

        // ---- 1. state update + segment-list write (st threads) ----
        float i_dec = 0.f;
        if (st) {
            float s = (0.0f - v) + 0.5f * expf((v - 1.0f) * 2.0f);
            s = s + cur;
            s = s - a;
            float v_dec = v + 0.1f * s;
            i_dec = cur - 0.2f * cur;
            float a_dec = a + 0.002f * (4.0f * v - a);
            bool  zk = (v_dec - 1.0f) > 0.0f;
            unsigned long long m = __ballot(zk);
            int c = (int)__popcll(m);
            unsigned long long below = (1ull << lane) - 1ull;
            if (lane == 0) scnt[cb][wv] = c;
            if (zk) {
                int off = (int)__popcll(m & below);
                seg[cb][wv][off] = (unsigned int)h << 11;
            } else {
                int pe = (c + 7) & ~7; if (pe < 8) pe = 8;  // pad to x8, min 8
                int ip = c + (int)__popcll(~m & below);
                if (ip < pe) seg[cb][wv][ip] = ZOFF;
            }
            v = zk ? 0.0f : v_dec;
            a = zk ? (a_dec + 0.02f) : a_dec;
        }

        // ---- 2. gather segment p of z(t-1) spikes (all threads) ----
        {
            const int n  = scnt[pv][p];            // wave-uniform
            const int ng = (n + 3) >> 2;
            const unsigned int* sp = &seg[pv][p][0];
            float4 rs = {0.f, 0.f, 0.f, 0.f};
            float4 b0[4], b1[4];
            auto ld4 = [&](int g, float4* d) {
                uint4 i0 = *(const uint4*)(sp + (g << 2));   // wave-uniform b128
                d[0] = *(const float4*)(WQ + i0.x);
                d[1] = *(const float4*)(WQ + i0.y);
                d[2] = *(const float4*)(WQ + i0.z);
                d[3] = *(const float4*)(WQ + i0.w);
            };
            auto acc4 = [&](const float4* d) {
#pragma unroll
                for (int u = 0; u < 4; ++u) {
                    rs.x += d[u].x; rs.y += d[u].y; rs.z += d[u].z; rs.w += d[u].w;
                }
            };
            ld4(0, b0);   // unconditional: entries 0..3 always real or ZOFF
            int g = 0;
            while (g + 2 <= ng) {
                ld4(g + 1, b1);
                acc4(b0);
                if (g + 2 < ng) ld4(g + 2, b0);
                acc4(b1);
                g += 2;
            }
            if (g < ng) acc4(b0);
            part[cb][p][q] = rs;
        }

        lds_barrier();   // the ONE barrier per step

        // ---- 4a. combine partials -> cur(t) (st threads) ----
        if (st) {
            float rec = 0.f;
#pragma unroll
            for (int pp = 0; pp < 8; ++pp)
                rec += ((const float*)&part[cb][pp][h >> 2])[h & 3];
            cur = (i_dec + icReg) + rec;          // consume iin[t] (2 steps old)
            if (t + 2 < T_STEPS)                  // reissue for t+2
                icReg = iin[((size_t)(t + 2) * BATCH + b) * HDIM + h];
        } else if (yrole) {
            // ---- 4b. fused y + exp-filter; PARALLEL static-address reads ----
            float acc = 0.f;
#pragma unroll
            for (int s = 0; s < 8; ++s) {
                uint4 eA = *(const uint4*)&seg[cb][s][0];   // broadcast b128
                uint4 eB = *(const uint4*)&seg[cb][s][4];
                unsigned a0 = yep ? eA.y : eA.x;
                unsigned a1 = yep ? eA.w : eA.z;
                unsigned a2 = yep ? eB.y : eB.x;
                unsigned a3 = yep ? eB.w : eB.z;
                float v0 = *(const float*)(WoB + (a0 >> 4));   // hp<<11 -> hp<<7
                float v1 = *(const float*)(WoB + (a1 >> 4));
                float v2 = *(const float*)(WoB + (a2 >> 4));
                float v3 = *(const float*)(WoB + (a3 >> 4));
                acc += (a0 == ZOFF) ? 0.f : v0;
                acc += (a1 == ZOFF) ? 0.f : v1;
                acc += (a2 == ZOFF) ? 0.f : v2;
                acc += (a3 == ZOFF) ? 0.f : v3;
            }
            // rare tail: segments with more than 8 spikes (real entries only)
#pragma unroll
            for (int s = 0; s < 8; ++s) {
                const int c = scnt[cb][s];
                if (c > 8) {
                    const unsigned int* sp = &seg[cb][s][0];
                    for (int e = 8 + yep; e < c; e += 2)
                        acc += *(const float*)(WoB + (sp[e] >> 4));
                }
            }
            float ytot = acc + __shfl_xor(acc, 32);
            float yv = ytot + bo;
            o_state = (t == 0) ? yv : (o_state + 0.2231435511314f * (yv - o_state));
            if (yep == 0)
                outF[(size_t)t * (BATCH * ODIM) + b * ODIM + yo] = o_state;
        }
    };

    for (int t = 0; t < T_STEPS; t += 2) {
        body(t,     0, icE);
        body(t + 1, 1, icO);
    }
}

// ---------------------------------------------------------------------------
// Readout from spike masks (bf16 path ONLY; fp32 path is fused into scan_f32).
// ---------------------------------------------------------------------------
__global__ __launch_bounds__(256) void y_kernel(const unsigned long long* __restrict__ masks,
                                                const float* __restrict__ WoutT,
                                                const float* __restrict__ bout,
                                                const int* __restrict__ flag,
                                                float* __restrict__ y) {
    if (*flag != 0) return;
    const int tid = threadIdx.x;
    const int p   = blockIdx.x * 8 + (tid >> 5);   // t*BATCH + b
    const int o   = tid & 31;
    const unsigned long long* mp = masks + (size_t)p * 8;
    float acc = 0.f;
#pragma unroll
    for (int w = 0; w < 8; ++w) {
        unsigned long long m = mp[w];
        const float* Wb = WoutT + (size_t)w * 64 * ODIM + o;
        while (m) {
            int j = __builtin_ctzll(m);
            acc += Wb[j * ODIM];
            m &= m - 1;
        }
    }
    y[(size_t)p * ODIM + o] = acc + bout[o];
}

// ---------------------------------------------------------------------------
// Exponential filter over t (bf16 path ONLY; fp32 fused into scan_f32).
// ---------------------------------------------------------------------------
__global__ __launch_bounds__(64) void filter_kernel(const float* __restrict__ y,
                                                    const int* __restrict__ flag,
                                                    void* __restrict__ out) {
    if (*flag != 0) return;
    const int p = blockIdx.x * 64 + threadIdx.x;   // b*ODIM + o
    const float kf = 0.2231435511314f;   // DT*TAU_FILTER_INV
    float c0[10], c1[10];
#pragma unroll
    for (int u = 0; u < 10; ++u) c0[u] = y[(size_t)u * (BATCH * ODIM) + p];
    float o_state = 0.f;
    for (int base = 0; base < T_STEPS; base += 10) {
        if (base + 10 < T_STEPS) {
#pragma unroll
            for (int u = 0; u < 10; ++u)
                c1[u] = y[(size_t)(base + 10 + u) * (BATCH * ODIM) + p];
        }
#pragma unroll
        for (int u = 0; u < 10; ++u) {
            int t = base + u;
            float yt = c0[u];
            o_state = (t == 0) ? yt : (o_state + kf * (yt - o_state));
            size_t oi = (size_t)t * (BATCH * ODIM) + p;
            ((__hip_bfloat16*)out)[oi] = __float2bfloat16(o_state);
        }
#pragma unroll
        for (int u = 0; u < 10; ++u) c0[u] = c1[u];
    }
}

// ---------------------------------------------------------------------------
extern "C" void kernel_launch(void* const* d_in, const int* in_sizes, int n_in,
                              void* d_out, int out_size, void* d_ws, size_t ws_size,
                              hipStream_t stream) {
    // select inputs by unique element count (robust to ordering)
    const void* x = d_in[0]; const void* Win = d_in[1]; const void* Wrec = d_in[2];
    const void* Wout = d_in[3]; const void* bout = d_in[4];
    for (int i = 0; i < n_in; ++i) {
        switch (in_sizes[i]) {
            case 8192000: x    = d_in[i]; break;
            case 65536:   Win  = d_in[i]; break;
            case 262144:  Wrec = d_in[i]; break;
            case 16384:   Wout = d_in[i]; break;
            case 32:      bout = d_in[i]; break;
            default: break;
        }
    }

    // workspace layout (bytes) — WrecTb (bf16) aliases WrecT (fp32) storage
    const size_t OFF_FLAG  = 0;          // 4
    const size_t OFF_BOUT  = 256;        // 128
    const size_t OFF_WOUTT = 512;        // 65536
    const size_t OFF_WRECT = 66048;      // 513*512*4 = 1050624 (or 513*512*2 bf16)
    const size_t OFF_WINT  = 1116672;    // 262144
    const size_t OFF_MASK  = 1378816;    // 500*128*8*8 = 4096000
    const size_t OFF_IIN   = 5474816;    // 64000*512*4 = 131072000
    const size_t OFF_Y     = OFF_IIN;    // y (8.2 MB) aliases iin (dead after scan)
    const size_t REQUIRED  = OFF_IIN + (size_t)M_ROWS * HDIM * 4;  // 136546816
    if (ws_size < REQUIRED) return;  // diagnostic: output stays 0

    char* ws = (char*)d_ws;
    int*            flag   = (int*)(ws + OFF_FLAG);
    float*          bout32 = (float*)(ws + OFF_BOUT);
    float*          WoutT  = (float*)(ws + OFF_WOUTT);
    float*          WrecT  = (float*)(ws + OFF_WRECT);
    unsigned short* WrecTb = (unsigned short*)(ws + OFF_WRECT);
    float*          WinT   = (float*)(ws + OFF_WINT);
    unsigned long long* masks = (unsigned long long*)(ws + OFF_MASK);
    float*          iin    = (float*)(ws + OFF_IIN);
    float*          y      = (float*)(ws + OFF_Y);

    hipLaunchKernelGGL(detect_kernel, dim3(1), dim3(256), 0, stream,
                       (const unsigned short*)x, flag);
    hipLaunchKernelGGL(prep_kernel, dim3((HDIM * HDIM + 255) / 256), dim3(256), 0, stream,
                       Wrec, Wout, bout, Win, flag, WrecT, WrecTb, WoutT, WinT, bout32);
    hipLaunchKernelGGL(iin_gemm_mfma, dim3(M_ROWS / 64, HDIM / 64), dim3(256), 0, stream,
                       (const __hip_bfloat16*)x, (const __hip_bfloat16*)Win, flag, iin);
    hipLaunchKernelGGL(iin_gemm_valu, dim3(M_ROWS / 32), dim3(256), 0, stream,
                       x, WinT, flag, iin);
    hipLaunchKernelGGL(scan_bf16, dim3(BATCH), dim3(1024), 0, stream,
                       iin, WrecTb, flag, masks);
    hipLaunchKernelGGL(scan_f32, dim3(BATCH), dim3(1024), 0, stream,
                       iin, WrecT, flag, WoutT, bout32, (float*)d_out);
    hipLaunchKernelGGL(y_kernel, dim3(M_ROWS / 8), dim3(256), 0, stream,
                       masks, WoutT, bout32, flag, y);
    hipLaunchKernelGGL(filter_kernel, dim3((BATCH * ODIM) / 64), dim3(64), 0, stream,
                       y, flag, d_out);
}

// Round 13
// 816.496 us; speedup vs baseline: 2.3633x; 1.3843x over previous
//
#include <hip/hip_runtime.h>
#include <hip/hip_bf16.h>
#include <cstdint>
#include <cstddef>

// Problem dims (fixed by reference)
#define T_STEPS 500
#define BATCH   128
#define FDIM    128
#define HDIM    512
#define ODIM    32
#define M_ROWS  (T_STEPS * BATCH)   // 64000
#define ZOFF    (512u << 11)        // zero-row byte offset, fp32 WrecT (2 KB rows)
#define ZOFFB   (512u << 10)        // zero-row byte offset, bf16 WrecTb (1 KB rows)

typedef __attribute__((ext_vector_type(8))) __bf16 bf16x8;
typedef __attribute__((ext_vector_type(4))) float  f32x4;

__device__ __forceinline__ float bfbits2f(unsigned short u) {
    union { unsigned int i; float f; } c; c.i = ((unsigned int)u) << 16; return c.f;
}
__device__ __forceinline__ float asf(unsigned int u) {
    union { unsigned int i; float f; } c; c.i = u; return c.f;
}
// LDS-only barrier: NO vmcnt drain (all cross-thread comms in the scan are LDS).
// HARDENED: sched_barrier(0) on both sides pins compiler instruction motion
// across the barrier — raw __builtin_amdgcn_s_barrier() is NOT a compiler
// memory fence (rule #18 class; R2/R4 failures attributed to this).
__device__ __forceinline__ void lds_barrier() {
    __builtin_amdgcn_sched_barrier(0);
    asm volatile("s_waitcnt lgkmcnt(0)" ::: "memory");
    __builtin_amdgcn_s_barrier();
    __builtin_amdgcn_sched_barrier(0);
}

// ---------------------------------------------------------------------------
// Dtype detect: flag=1 means fp32 inputs, flag=0 means bf16.
// ---------------------------------------------------------------------------
__global__ void detect_kernel(const unsigned short* __restrict__ xw, int* __restrict__ flag) {
    __shared__ int cnt;
    if (threadIdx.x == 0) cnt = 0;
    __syncthreads();
    unsigned short w = xw[threadIdx.x * 2];
    int e = (w >> 7) & 0xFF;
    if (e >= 170) atomicAdd(&cnt, 1);
    __syncthreads();
    if (threadIdx.x == 0) *flag = (cnt >= 8) ? 1 : 0;
}

// ---------------------------------------------------------------------------
// Prep. flag==0 (bf16): WrecTb[hp][h] = raw bf16 bits of W_rec[h][hp] (+zero row).
//       flag==1 (fp32): WrecT fp32 transpose (+zero row), WinT fp32 transpose.
// WoutT (fp32 [h][o]) and bout32 built either way. WrecTb aliases WrecT storage.
// ---------------------------------------------------------------------------
__global__ void prep_kernel(const void* __restrict__ Wrec,
                            const void* __restrict__ Wout,
                            const void* __restrict__ bout,
                            const void* __restrict__ Win,
                            const int* __restrict__ flag,
                            float* __restrict__ WrecT,
                            unsigned short* __restrict__ WrecTb,
                            float* __restrict__ WoutT,
                            float* __restrict__ WinT,
                            float* __restrict__ bout32) {
    const int fp32 = *flag;
    int idx = blockIdx.x * blockDim.x + threadIdx.x;
    if (fp32) {
        if (idx < HDIM * HDIM) {
            int h = idx / HDIM, hp = idx % HDIM;
            WrecT[hp * HDIM + h] = ((const float*)Wrec)[idx];
        }
        if (idx < HDIM) WrecT[HDIM * HDIM + idx] = 0.f;
        if (idx < HDIM * FDIM) {
            int h = idx / FDIM, f = idx % FDIM;
            WinT[f * HDIM + h] = ((const float*)Win)[idx];
        }
    } else {
        if (idx < HDIM * HDIM) {
            int h = idx / HDIM, hp = idx % HDIM;
            WrecTb[hp * HDIM + h] = ((const unsigned short*)Wrec)[idx];
        }
        if (idx < HDIM) WrecTb[HDIM * HDIM + idx] = 0;
    }
    if (idx < ODIM * HDIM) {
        int o = idx / HDIM, h = idx % HDIM;
        WoutT[h * ODIM + o] = fp32 ? ((const float*)Wout)[idx]
                                   : bfbits2f(((const unsigned short*)Wout)[idx]);
    }
    if (idx < ODIM)
        bout32[idx] = fp32 ? ((const float*)bout)[idx]
                           : bfbits2f(((const unsigned short*)bout)[idx]);
}

// ---------------------------------------------------------------------------
// i_in GEMM, MFMA path (flag==0, bf16 inputs). 16x16x32 bf16 MFMA.
// ---------------------------------------------------------------------------
__global__ __launch_bounds__(256) void iin_gemm_mfma(const __hip_bfloat16* __restrict__ x,
                                                     const __hip_bfloat16* __restrict__ Win,
                                                     const int* __restrict__ flag,
                                                     float* __restrict__ iin) {
    if (*flag != 0) return;
    const int mt   = blockIdx.x;       // 0..999
    const int nt   = blockIdx.y;       // 0..7
    const int wave = threadIdx.x >> 6;
    const int lane = threadIdx.x & 63;
    const int l15  = lane & 15;
    const int quad = lane >> 4;
    const int m_base = mt * 64 + wave * 16;
    const int n_base = nt * 64;

    const __bf16* xb = reinterpret_cast<const __bf16*>(x);
    const __bf16* wb = reinterpret_cast<const __bf16*>(Win);

    f32x4 acc[4] = {{0.f,0.f,0.f,0.f},{0.f,0.f,0.f,0.f},{0.f,0.f,0.f,0.f},{0.f,0.f,0.f,0.f}};

#pragma unroll
    for (int kk = 0; kk < 4; ++kk) {
        const int k0 = kk * 32 + quad * 8;
        bf16x8 a = *reinterpret_cast<const bf16x8*>(xb + (size_t)(m_base + l15) * FDIM + k0);
#pragma unroll
        for (int nb = 0; nb < 4; ++nb) {
            bf16x8 bf = *reinterpret_cast<const bf16x8*>(wb + (size_t)(n_base + nb * 16 + l15) * FDIM + k0);
            acc[nb] = __builtin_amdgcn_mfma_f32_16x16x32_bf16(a, bf, acc[nb], 0, 0, 0);
        }
    }

#pragma unroll
    for (int nb = 0; nb < 4; ++nb)
#pragma unroll
        for (int r = 0; r < 4; ++r)
            iin[(size_t)(m_base + quad * 4 + r) * HDIM + n_base + nb * 16 + l15] = acc[nb][r];
}

// ---------------------------------------------------------------------------
// i_in GEMM, fp32 VALU fallback (flag==1) — R5 version (passing).
// ---------------------------------------------------------------------------
__global__ __launch_bounds__(256) void iin_gemm_valu(const void* __restrict__ x,
                                                     const float* __restrict__ WinT,
                                                     const int* __restrict__ flag,
                                                     float* __restrict__ iin) {
    if (*flag != 1) return;
    const int tid = threadIdx.x;
    const int m0  = blockIdx.x * 32;
    const int tg  = tid >> 6;          // m-group 0..3 -> rows tg*8..tg*8+7
    const int n0  = (tid & 63) * 8;    // output cols n0..n0+7

    __shared__ alignas(16) float xs[32][FDIM];   // 16 KB, [m][k]

    for (int i = tid; i < 32 * FDIM; i += 256)
        xs[0][i] = ((const float*)x)[(size_t)m0 * FDIM + i];
    __syncthreads();

    const float4* xs4 = reinterpret_cast<const float4*>(&xs[tg * 8][0]);

    float acc[8][8];
#pragma unroll
    for (int i = 0; i < 8; ++i)
#pragma unroll
        for (int j = 0; j < 8; ++j) acc[i][j] = 0.f;

    auto ldw = [&](int k4, float (*w)[8]) {
#pragma unroll
        for (int u = 0; u < 4; ++u) {
            const float* wp = WinT + (size_t)(k4 * 4 + u) * HDIM + n0;
            float4 a = *(const float4*)(wp);
            float4 b = *(const float4*)(wp + 4);
            w[u][0] = a.x; w[u][1] = a.y; w[u][2] = a.z; w[u][3] = a.w;
            w[u][4] = b.x; w[u][5] = b.y; w[u][6] = b.z; w[u][7] = b.w;
        }
    };
    auto cmp = [&](int k4, const float (*w)[8]) {
#pragma unroll
        for (int i = 0; i < 8; ++i) {
            float4 xv = xs4[i * (FDIM / 4) + k4];
#pragma unroll
            for (int j = 0; j < 8; ++j)
                acc[i][j] += xv.x * w[0][j] + xv.y * w[1][j]
                           + xv.z * w[2][j] + xv.w * w[3][j];
        }
    };

    float wA[4][8], wB[4][8];
    ldw(0, wA);
    for (int k4 = 0; k4 < FDIM / 4; k4 += 2) {
        ldw(k4 + 1, wB);
        cmp(k4, wA);
        if (k4 + 2 < FDIM / 4) ldw(k4 + 2, wA);
        cmp(k4 + 1, wB);
    }

#pragma unroll
    for (int i = 0; i < 8; ++i) {
        float4 lo = {acc[i][0], acc[i][1], acc[i][2], acc[i][3]};
        float4 hi = {acc[i][4], acc[i][5], acc[i][6], acc[i][7]};
        float* op = iin + (size_t)(m0 + tg * 8 + i) * HDIM + n0;
        *(float4*)(op)     = lo;
        *(float4*)(op + 4) = hi;
    }
}

// ---------------------------------------------------------------------------
// Scan, bf16-weight path (flag==0). 128 WGs, 1024 threads. (Unchanged, known good.)
// ---------------------------------------------------------------------------
__global__ __launch_bounds__(1024) void scan_bf16(const float* __restrict__ iin,
                                                  const unsigned short* __restrict__ WrecTb,
                                                  const int* __restrict__ flag,
                                                  unsigned long long* __restrict__ masksG) {
    if (*flag != 0) return;
    const int b    = blockIdx.x;
    const int tid  = threadIdx.x;
    const int q    = tid & 63;          // neuron octet base h = 8q
    const int pc   = tid >> 6;          // parity class (== wave) 0..15
    const int lane = tid & 63;
    const int wv   = tid >> 6;
    const bool st  = tid < HDIM;        // state-owning threads
    const int h    = tid;

    __shared__ unsigned long long wmask[8];
    __shared__ float4 partA[16][64];                    // 4 KB
    __shared__ float4 partB[16][64];                    // 4 KB
    __shared__ alignas(16) unsigned int slA[16][36];    // double-buffered lists
    __shared__ alignas(16) unsigned int slB[16][36];
    unsigned int (*slO)[36] = slA;
    unsigned int (*slN)[36] = slB;

    float v = 0.f, cur = 0.f, a = 0.f;
    int   cnt = 0;
    const char* WQ = (const char*)WrecTb + q * 16;   // + (hp<<10) -> row hp, cols 8q..8q+7
    float ic_cur = st ? iin[(size_t)b * HDIM + h] : 0.f;   // t = 0

    for (int t = 0; t < T_STEPS; ++t) {
        // prefetch next step's feed-forward current (slack ~ full step)
        float ic_next = 0.f;
        if (st && (t + 1) < T_STEPS)
            ic_next = iin[((size_t)(t + 1) * BATCH + b) * HDIM + h];

        float i_dec = 0.f; bool zk = false; unsigned long long m = 0;
        if (st) {
            float s = (0.0f - v) + 0.5f * expf((v - 1.0f) * 2.0f);
            s = s + cur;
            s = s - a;
            float v_dec = v + 0.1f * s;
            i_dec = cur - 0.2f * cur;
            float a_dec = a + 0.002f * (4.0f * v - a);
            zk = (v_dec - 1.0f) > 0.0f;
            m = __ballot(zk);
            if (lane == 0) {
                wmask[wv] = m;
                masksG[((size_t)t * BATCH + b) * 8 + wv] = m;   // fire-and-forget
            }
            v = zk ? 0.0f : v_dec;
            a = zk ? (a_dec + 0.02f) : a_dec;
        }

        // ---- gather my parity class of PREVIOUS spikes (8 weights / load) ----
        float rs0=0.f,rs1=0.f,rs2=0.f,rs3=0.f,rs4=0.f,rs5=0.f,rs6=0.f,rs7=0.f;
        {
            const unsigned int* sl = slO[pc];
            const int n  = (cnt + 15 - pc) >> 4;   // my sub-list length
            const int ng = (n + 3) >> 2;           // padded groups of 4
            uint4 w0[4], w1[4];
            auto ldg = [&](int g, uint4* w) {
                uint4 ix = *(const uint4*)(sl + (g << 2));   // wave-uniform b128
                w[0] = *(const uint4*)(WQ + ix.x);
                w[1] = *(const uint4*)(WQ + ix.y);
                w[2] = *(const uint4*)(WQ + ix.z);
                w[3] = *(const uint4*)(WQ + ix.w);
            };
            auto accw = [&](const uint4* w) {
#pragma unroll
                for (int u = 0; u < 4; ++u) {
                    rs0 += asf(w[u].x << 16); rs1 += asf(w[u].x & 0xffff0000u);
                    rs2 += asf(w[u].y << 16); rs3 += asf(w[u].y & 0xffff0000u);
                    rs4 += asf(w[u].z << 16); rs5 += asf(w[u].z & 0xffff0000u);
                    rs6 += asf(w[u].w << 16); rs7 += asf(w[u].w & 0xffff0000u);
                }
            };
            int g = 0;
            if (ng > 0) ldg(0, w0);
            while (g + 2 <= ng) {
                ldg(g + 1, w1);
                accw(w0);
                if (g + 2 < ng) ldg(g + 2, w0);
                accw(w1);
                g += 2;
            }
            if (g < ng) accw(w0);
        }
        partA[pc][q] = (float4){rs0, rs1, rs2, rs3};
        partB[pc][q] = (float4){rs4, rs5, rs6, rs7};

        lds_barrier();   // B1: wmask + partials visible; slO fully consumed

        int total = 0;
#pragma unroll
        for (int w = 0; w < 8; ++w) total += __popcll(wmask[w]);

        if (st) {
            // combine partials, ascending pc (deterministic)
            float rec = 0.f;
            const int  qq = h >> 3, jj = h & 3;
            const bool hi = (h & 4) != 0;
#pragma unroll
            for (int pp = 0; pp < 16; ++pp) {
                const float* pa = (const float*)&partA[pp][qq];
                const float* pb = (const float*)&partB[pp][qq];
                rec += hi ? pb[jj] : pa[jj];
            }
            cur = (i_dec + ic_cur) + rec;

            if (zk) {
                int off = __popcll(m & ((1ull << lane) - 1ull));
#pragma unroll
                for (int w = 0; w < 8; ++w) if (w < wv) off += __popcll(wmask[w]);
                slN[off & 15][off >> 4] = (unsigned int)h << 10;
            }
        } else if (tid < HDIM + 64) {
            // zero-row padding: sub-list s5 padded to multiple of 4
            int s5 = (tid - HDIM) >> 2;
            int k  = (tid - HDIM) & 3;
            int ne = (total + 15 - s5) >> 4;
            int padc = (4 - (ne & 3)) & 3;
            if (k < padc) slN[s5][ne + k] = ZOFFB;
        }
        cnt = total;
        ic_cur = ic_next;

        lds_barrier();   // B2: new lists complete before next step's gather

        unsigned int (*tp)[36] = slO; slO = slN; slN = tp;
    }
}

// ---------------------------------------------------------------------------
// Scan, fp32 path (flag==1) — FINAL (R10): R6 single-barrier structure
// + 2-deep iin prefetch (icE/icO) + setprio(1) on state waves.
// Verified 548 us scan / 821.5 us total, absmax 9.77e-4, replay-stable.
// Structural floor: 500 serial steps x ~2650 cy (recurrence dependency
// chain: list write -> barrier -> LDS index read -> L2 gather -> combine).
// Seven structural variants (2-barrier, role-split, own-column, batch-
// amortized, fused-readout) all landed at or above this plateau.
// ---------------------------------------------------------------------------
__global__ __launch_bounds__(1024) void scan_f32(const float* __restrict__ iin,
                                                 const float* __restrict__ WrecT,
                                                 const int* __restrict__ flag,
                                                 unsigned long long* __restrict__ masksG) {
    if (*flag != 1) return;
    const int b    = blockIdx.x;
    const int tid  = threadIdx.x;
    const int lane = tid & 63;
    const int wv   = tid >> 6;          // 0..15
    const bool st  = tid < HDIM;
    const int h    = tid;               // neuron index (st threads)
    const int p    = tid >> 7;          // gather class == segment 0..7
    const int q    = tid & 127;         // 16B column block (cols 4q..4q+3)

    __shared__ alignas(16) unsigned int seg[2][8][64];  // 4 KB: byte offs hp<<11
    __shared__ int scnt[2][8];
    __shared__ float4 part[2][8][128];                  // 32 KB

    // init prev-buffer (index 1): empty lists, valid ZOFF targets
    if (tid < 8) scnt[1][tid] = 0;
    if (tid < 512) ((unsigned int*)seg[1])[tid] = ZOFF;
    lds_barrier();

    // prioritize the critical-path (state) waves; wave-uniform branch
    if (st) __builtin_amdgcn_s_setprio(1);

    float v = 0.f, cur = 0.f, a = 0.f;
    const char* WQ = (const char*)WrecT + q * 16;

    // 2-deep iin prefetch registers (consumed at body t, reloaded t+2)
    float icE = st ? iin[((size_t)0 * BATCH + b) * HDIM + h] : 0.f;
    float icO = st ? iin[((size_t)1 * BATCH + b) * HDIM + h] : 0.f;

    auto body = [&](int t, int cb, float& icReg) {
        const int pv = cb ^ 1;

        // ---- 1. state update + segment-list write (st threads) ----
        float i_dec = 0.f;
        if (st) {
            float s = (0.0f - v) + 0.5f * expf((v - 1.0f) * 2.0f);
            s = s + cur;
            s = s - a;
            float v_dec = v + 0.1f * s;
            i_dec = cur - 0.2f * cur;
            float a_dec = a + 0.002f * (4.0f * v - a);
            bool  zk = (v_dec - 1.0f) > 0.0f;
            unsigned long long m = __ballot(zk);
            int c = (int)__popcll(m);
            unsigned long long below = (1ull << lane) - 1ull;
            if (lane == 0) {
                scnt[cb][wv] = c;
                masksG[((size_t)t * BATCH + b) * 8 + wv] = m;   // fire-and-forget
            }
            if (zk) {
                int off = (int)__popcll(m & below);
                seg[cb][wv][off] = (unsigned int)h << 11;
            } else {
                int pe = (c + 3) & ~3; pe = (pe < 4) ? 4 : pe;  // pad to x4, min 4
                int ip = c + (int)__popcll(~m & below);
                if (ip < pe) seg[cb][wv][ip] = ZOFF;
            }
            v = zk ? 0.0f : v_dec;
            a = zk ? (a_dec + 0.02f) : a_dec;
        }

        // ---- 2. gather segment p of z(t-1) spikes (all threads) ----
        {
            const int n  = scnt[pv][p];            // wave-uniform
            const int ng = (n + 3) >> 2;
            const unsigned int* sp = &seg[pv][p][0];
            float4 rs = {0.f, 0.f, 0.f, 0.f};
            float4 b0[4], b1[4];
            auto ld4 = [&](int g, float4* d) {
                uint4 i0 = *(const uint4*)(sp + (g << 2));   // wave-uniform b128
                d[0] = *(const float4*)(WQ + i0.x);
                d[1] = *(const float4*)(WQ + i0.y);
                d[2] = *(const float4*)(WQ + i0.z);
                d[3] = *(const float4*)(WQ + i0.w);
            };
            auto acc4 = [&](const float4* d) {
#pragma unroll
                for (int u = 0; u < 4; ++u) {
                    rs.x += d[u].x; rs.y += d[u].y; rs.z += d[u].z; rs.w += d[u].w;
                }
            };
            ld4(0, b0);   // unconditional: entries 0..3 always real or ZOFF
            int g = 0;
            while (g + 2 <= ng) {
                ld4(g + 1, b1);
                acc4(b0);
                if (g + 2 < ng) ld4(g + 2, b0);
                acc4(b1);
                g += 2;
            }
            if (g < ng) acc4(b0);
            part[cb][p][q] = rs;
        }

        lds_barrier();   // the ONE barrier per step

        // ---- 4. combine partials -> cur(t) (st threads) ----
        if (st) {
            float rec = 0.f;
#pragma unroll
            for (int pp = 0; pp < 8; ++pp)
                rec += ((const float*)&part[cb][pp][h >> 2])[h & 3];
            cur = (i_dec + icReg) + rec;          // consume iin[t] (2 steps old)
            if (t + 2 < T_STEPS)                  // reissue for t+2
                icReg = iin[((size_t)(t + 2) * BATCH + b) * HDIM + h];
        }
    };

    for (int t = 0; t < T_STEPS; t += 2) {
        body(t,     0, icE);
        body(t + 1, 1, icO);
    }
}

// ---------------------------------------------------------------------------
// Readout from spike masks: y[t][b][o] = sum_{h' spiking} WoutT[h'][o] + b[o]
// ---------------------------------------------------------------------------
__global__ __launch_bounds__(256) void y_kernel(const unsigned long long* __restrict__ masks,
                                                const float* __restrict__ WoutT,
                                                const float* __restrict__ bout,
                                                float* __restrict__ y) {
    const int tid = threadIdx.x;
    const int p   = blockIdx.x * 8 + (tid >> 5);   // t*BATCH + b
    const int o   = tid & 31;
    const unsigned long long* mp = masks + (size_t)p * 8;
    float acc = 0.f;
#pragma unroll
    for (int w = 0; w < 8; ++w) {
        unsigned long long m = mp[w];
        const float* Wb = WoutT + (size_t)w * 64 * ODIM + o;
        while (m) {
            int j = __builtin_ctzll(m);
            acc += Wb[j * ODIM];
            m &= m - 1;
        }
    }
    y[(size_t)p * ODIM + o] = acc + bout[o];
}

// ---------------------------------------------------------------------------
// Exponential filter over t: 4096 independent (b,o) chains; chunked prefetch.
// ---------------------------------------------------------------------------
__global__ __launch_bounds__(64) void filter_kernel(const float* __restrict__ y,
                                                    const int* __restrict__ flag,
                                                    void* __restrict__ out) {
    const int p = blockIdx.x * 64 + threadIdx.x;   // b*ODIM + o
    const int fp32o = *flag;
    const float kf = 0.2231435511314f;   // DT*TAU_FILTER_INV
    float c0[10], c1[10];
#pragma unroll
    for (int u = 0; u < 10; ++u) c0[u] = y[(size_t)u * (BATCH * ODIM) + p];
    float o_state = 0.f;
    for (int base = 0; base < T_STEPS; base += 10) {
        if (base + 10 < T_STEPS) {
#pragma unroll
            for (int u = 0; u < 10; ++u)
                c1[u] = y[(size_t)(base + 10 + u) * (BATCH * ODIM) + p];
        }
#pragma unroll
        for (int u = 0; u < 10; ++u) {
            int t = base + u;
            float yt = c0[u];
            o_state = (t == 0) ? yt : (o_state + kf * (yt - o_state));
            size_t oi = (size_t)t * (BATCH * ODIM) + p;
            if (fp32o) ((float*)out)[oi] = o_state;
            else       ((__hip_bfloat16*)out)[oi] = __float2bfloat16(o_state);
        }
#pragma unroll
        for (int u = 0; u < 10; ++u) c0[u] = c1[u];
    }
}

// ---------------------------------------------------------------------------
extern "C" void kernel_launch(void* const* d_in, const int* in_sizes, int n_in,
                              void* d_out, int out_size, void* d_ws, size_t ws_size,
                              hipStream_t stream) {
    // select inputs by unique element count (robust to ordering)
    const void* x = d_in[0]; const void* Win = d_in[1]; const void* Wrec = d_in[2];
    const void* Wout = d_in[3]; const void* bout = d_in[4];
    for (int i = 0; i < n_in; ++i) {
        switch (in_sizes[i]) {
            case 8192000: x    = d_in[i]; break;
            case 65536:   Win  = d_in[i]; break;
            case 262144:  Wrec = d_in[i]; break;
            case 16384:   Wout = d_in[i]; break;
            case 32:      bout = d_in[i]; break;
            default: break;
        }
    }

    // workspace layout (bytes) — WrecTb (bf16) aliases WrecT (fp32) storage
    const size_t OFF_FLAG  = 0;          // 4
    const size_t OFF_BOUT  = 256;        // 128
    const size_t OFF_WOUTT = 512;        // 65536
    const size_t OFF_WRECT = 66048;      // 513*512*4 = 1050624 (or 513*512*2 bf16)
    const size_t OFF_WINT  = 1116672;    // 262144
    const size_t OFF_MASK  = 1378816;    // 500*128*8*8 = 4096000
    const size_t OFF_IIN   = 5474816;    // 64000*512*4 = 131072000
    const size_t OFF_Y     = OFF_IIN;    // y (8.2 MB) aliases iin (dead after scan)
    const size_t REQUIRED  = OFF_IIN + (size_t)M_ROWS * HDIM * 4;  // 136546816
    if (ws_size < REQUIRED) return;  // diagnostic: output stays 0

    char* ws = (char*)d_ws;
    int*            flag   = (int*)(ws + OFF_FLAG);
    float*          bout32 = (float*)(ws + OFF_BOUT);
    float*          WoutT  = (float*)(ws + OFF_WOUTT);
    float*          WrecT  = (float*)(ws + OFF_WRECT);
    unsigned short* WrecTb = (unsigned short*)(ws + OFF_WRECT);
    float*          WinT   = (float*)(ws + OFF_WINT);
    unsigned long long* masks = (unsigned long long*)(ws + OFF_MASK);
    float*          iin    = (float*)(ws + OFF_IIN);
    float*          y      = (float*)(ws + OFF_Y);

    hipLaunchKernelGGL(detect_kernel, dim3(1), dim3(256), 0, stream,
                       (const unsigned short*)x, flag);
    hipLaunchKernelGGL(prep_kernel, dim3((HDIM * HDIM + 255) / 256), dim3(256), 0, stream,
                       Wrec, Wout, bout, Win, flag, WrecT, WrecTb, WoutT, WinT, bout32);
    hipLaunchKernelGGL(iin_gemm_mfma, dim3(M_ROWS / 64, HDIM / 64), dim3(256), 0, stream,
                       (const __hip_bfloat16*)x, (const __hip_bfloat16*)Win, flag, iin);
    hipLaunchKernelGGL(iin_gemm_valu, dim3(M_ROWS / 32), dim3(256), 0, stream,
                       x, WinT, flag, iin);
    hipLaunchKernelGGL(scan_bf16, dim3(BATCH), dim3(1024), 0, stream,
                       iin, WrecTb, flag, masks);
    hipLaunchKernelGGL(scan_f32, dim3(BATCH), dim3(1024), 0, stream,
                       iin, WrecT, flag, masks);
    hipLaunchKernelGGL(y_kernel, dim3(M_ROWS / 8), dim3(256), 0, stream,
                       masks, WoutT, bout32, y);
    hipLaunchKernelGGL(filter_kernel, dim3((BATCH * ODIM) / 64), dim3(64), 0, stream,
                       y, flag, d_out);
}